// Round 11
// baseline (139.865 us; speedup 1.0000x reference)
//
#include <hip/hip_runtime.h>
#include <math.h>

#define NN 325
#define BT 96
#define NROWS (BT * NN)   // 31200
// fold softmax scale and log2(e) into q: exp(s/sqrt8) == exp2(s * SCL)
#define SCL (0.35355339059327373f * 1.4426950408889634f)
#define QKV_BLKS ((NROWS + 63) / 64)        // 488
#define PREP_ITEMS (11 * NN + 8192)         // 3575 masks + 8192 wab = 11767
#define PREP_BLKS ((PREP_ITEMS + 511) / 512) // 23
#define TOT_BLKS (QKV_BLKS + PREP_BLKS)     // 511
#define HSTR (NN * 8)                        // 2600 halfs per (bt,h) plane

typedef _Float16 half_t;
typedef half_t half8_t __attribute__((ext_vector_type(8)));
typedef half_t half4_t __attribute__((ext_vector_type(4)));
typedef half_t half2_t __attribute__((ext_vector_type(2)));
typedef float float4_t __attribute__((ext_vector_type(4)));

// Exact-enough gelu: A&S 7.1.26 rational erf (|err| <= 1.5e-7, invisible at f16)
__device__ __forceinline__ float gelu_f(float x) {
    const float z  = 0.70710678118654752f * x;
    const float az = __builtin_fabsf(z);
    const float t  = __builtin_amdgcn_rcpf(__builtin_fmaf(0.3275911f, az, 1.0f));
    float p = __builtin_fmaf(1.061405429f, t, -1.453152027f);
    p = __builtin_fmaf(p, t, 1.421413741f);
    p = __builtin_fmaf(p, t, -0.284496736f);
    p = __builtin_fmaf(p, t, 0.254829592f);
    p *= t;
    const float e = __builtin_amdgcn_exp2f(-az * az * 1.4426950408889634f);
    float er = __builtin_fmaf(-p, e, 1.0f);
    er = __builtin_copysignf(er, z);
    return 0.5f * x * (1.0f + er);
}

#define XS 136   // half stride per 128-k row (qkv)
#define PS 72    // half stride per 64-k row (proj)

// Stage a 64x128 f32 weight matrix into LDS as f16.
__device__ __forceinline__ void qkv_stage_wf(const float* __restrict__ src,
                                             half_t* dst, int tid)
{
    #pragma unroll
    for (int idx = tid; idx < 1024; idx += 512) {
        int c = idx >> 4, g = idx & 15;
        const float4* s4 = (const float4*)&src[c * 128 + g * 8];
        float4 a = s4[0], b = s4[1];
        half8_t h;
        h[0] = (half_t)a.x; h[1] = (half_t)a.y;
        h[2] = (half_t)a.z; h[3] = (half_t)a.w;
        h[4] = (half_t)b.x; h[5] = (half_t)b.y;
        h[6] = (half_t)b.z; h[7] = (half_t)b.w;
        *(half8_t*)&dst[c * XS + g * 8] = h;
    }
}

// q/k/v are written HEAD-MAJOR: plane (bt*8+h) of [NN][8] halfs, so attn
// reads are fully dense (5.2 KB/tensor/block, zero overfetch).
__device__ __forceinline__ void qkv_compute(
    const half_t* x16, const half_t* wb, const float* __restrict__ b,
    half_t* __restrict__ outp, float oscale,
    int row0, int rbase, int ch, int l15, int quad)
{
    float4_t acc[2];
    #pragma unroll
    for (int cc = 0; cc < 2; ++cc) {
        float bias = b[(ch * 2 + cc) * 16 + l15];
        acc[cc] = (float4_t){bias, bias, bias, bias};
    }
    #pragma unroll
    for (int kk = 0; kk < 8; ++kk) {
        half4_t a = *(const half4_t*)&x16[(rbase + l15) * XS + kk * 16 + quad * 4];
        #pragma unroll
        for (int cc = 0; cc < 2; ++cc) {
            half4_t bf = *(const half4_t*)
                &wb[((ch * 2 + cc) * 16 + l15) * XS + kk * 16 + quad * 4];
            acc[cc] = __builtin_amdgcn_mfma_f32_16x16x16f16(a, bf, acc[cc], 0, 0, 0);
        }
    }
    #pragma unroll
    for (int rr = 0; rr < 4; ++rr) {
        int R = row0 + rbase + quad * 4 + rr;
        if (R < NROWS) {
            int bt = R / NN, n = R - bt * NN;   // magic-mul div by const
            #pragma unroll
            for (int cc = 0; cc < 2; ++cc) {
                int col = (ch * 2 + cc) * 16 + l15;
                outp[(long)((bt << 3) + (col >> 3)) * HSTR + n * 8 + (col & 7)] =
                    (half_t)(gelu_f(acc[cc][rr]) * oscale);
            }
        }
    }
}

// ---------------------------------------------------------------------------
// Kernel 1: q/k/v = gelu(concat(X,STE) @ W.T + b) via f16 MFMA.
// r4 ping-pong structure (best measured). Blocks [488,511): prep work.
// ---------------------------------------------------------------------------
__global__ __launch_bounds__(512) void qkv_kernel(
    const float* __restrict__ X, const float* __restrict__ STE,
    const int* __restrict__ adj,
    const float* __restrict__ W7, const float* __restrict__ b7,
    const float* __restrict__ W8, const float* __restrict__ b8,
    const float* __restrict__ W9, const float* __restrict__ b9,
    const float* __restrict__ W10, const float* __restrict__ W11,
    half_t* __restrict__ q, half_t* __restrict__ k, half_t* __restrict__ v,
    unsigned int* __restrict__ packedT, half_t* __restrict__ wab)
{
    const int tid = threadIdx.x;
    const int bx  = blockIdx.x;

    if (bx >= QKV_BLKS) {
        // ------- prep tail blocks: masks + W10/W11 f16 conversion ---------
        int idx = (bx - QKV_BLKS) * 512 + tid;
        if (idx < 11 * NN) {
            int w = idx / NN, n = idx - w * NN;
            unsigned int bits = 0u;
            #pragma unroll 8
            for (int j = 0; j < 32; ++j) {
                int m = w * 32 + j;
                if (m < NN && adj[n * NN + m] > 0) bits |= (1u << j);
            }
            packedT[w * NN + n] = bits;
        } else if (idx < PREP_ITEMS) {
            int i = idx - 11 * NN;
            int p = i >> 12, r = i & 4095;
            wab[i] = (half_t)(p ? W11[r] : W10[r]);
        }
        return;
    }

    __shared__ __attribute__((aligned(16))) half_t x16[64 * XS];
    __shared__ __attribute__((aligned(16))) half_t wbuf[2][64 * XS];
    const int row0 = bx * 64;

    // stage x = concat(X, STE) -> f16
    #pragma unroll
    for (int idx = tid; idx < 2048; idx += 512) {
        int r = idx >> 5, c4 = idx & 31;
        int R = row0 + r;
        float4 f = {0.f, 0.f, 0.f, 0.f};
        if (R < NROWS)
            f = (c4 < 16) ? *(const float4*)(X + R * 64 + c4 * 4)
                          : *(const float4*)(STE + R * 64 + (c4 - 16) * 4);
        half4_t hv;
        hv[0] = (half_t)f.x; hv[1] = (half_t)f.y;
        hv[2] = (half_t)f.z; hv[3] = (half_t)f.w;
        *(half4_t*)&x16[r * XS + c4 * 4] = hv;
    }
    qkv_stage_wf(W7, wbuf[0], tid);          // W7 (f32 -> f16 inline)
    __syncthreads();

    const int lane = tid & 63, wv = tid >> 6;
    const int l15 = lane & 15, quad = lane >> 4;
    const int rbase = (wv & 3) * 16, ch = wv >> 2;

    qkv_stage_wf(W8, wbuf[1], tid);          // W8 (overlaps phase 0)
    qkv_compute(x16, wbuf[0], b7, q, SCL, row0, rbase, ch, l15, quad);
    __syncthreads();

    qkv_stage_wf(W9, wbuf[0], tid);          // W9 (overlaps phase 1)
    qkv_compute(x16, wbuf[1], b8, k, 1.0f, row0, rbase, ch, l15, quad);
    __syncthreads();

    qkv_compute(x16, wbuf[0], b9, v, 1.0f, row0, rbase, ch, l15, quad);
}

// ---------------------------------------------------------------------------
// Kernel 2: MFMA flash attention (r9-verified): single-pass norm-bound +
// XCD swizzle + head-major dense q/k/v reads.
// ---------------------------------------------------------------------------
__global__ __launch_bounds__(512) void attn_kernel(
    const half_t* __restrict__ q16g, const half_t* __restrict__ k16g,
    const half_t* __restrict__ v16g, const unsigned int* __restrict__ packedT,
    half_t* __restrict__ ao)
{
    __shared__ __attribute__((aligned(16))) half_t K16[336 * 20]; // [m][d0..15,pad]
    __shared__ __attribute__((aligned(16))) half_t VT16[16 * 344];// [c][m]
    __shared__ float smax8[8];
    const int tid = threadIdx.x;
    const int bx  = blockIdx.x;
    const int h   = bx / BT;          // 0..7
    const int bt  = bx - h * BT;      // 0..95 ; id%8 == bt%8 -> same XCD
    const long qbase = (long)((bt << 3) + h) * HSTR;       // head-major plane
    const long baseO = (long)(bt * NN) * 64 + h * 8;       // ao (row-major)

    const half4_t z4 = {(half_t)0.f, (half_t)0.f, (half_t)0.f, (half_t)0.f};

    // zero VT16 except ones-row c=8 (disjoint -> no barrier needed between)
    for (int idx = tid; idx < 16 * 344 / 2; idx += 512)
        if (idx < 1376 || idx >= 1548)            // skip row 8 (half2 idx)
            ((half2_t*)VT16)[idx] = (half2_t)(half_t)0.f;
    for (int i = tid; i < 344; i += 512)
        VT16[8 * 344 + i] = (half_t)1.0f;

    // stage K rows (dense 16B/row) + per-row |k|^2
    float nk2 = 0.0f;
    for (int r = tid; r < 336; r += 512) {
        half4_t ka = z4, kbv = z4;
        if (r < NN) {
            ka  = *(const half4_t*)(k16g + qbase + r * 8);
            kbv = *(const half4_t*)(k16g + qbase + r * 8 + 4);
        }
        *(half4_t*)&K16[r * 20]      = ka;
        *(half4_t*)&K16[r * 20 + 4]  = kbv;
        *(half4_t*)&K16[r * 20 + 8]  = z4;
        *(half4_t*)&K16[r * 20 + 12] = z4;
        #pragma unroll
        for (int j = 0; j < 4; ++j) {
            float fa = (float)ka[j], fb = (float)kbv[j];
            nk2 = fmaf(fa, fa, nk2);
            nk2 = fmaf(fb, fb, nk2);
        }
    }

    // stage V transposed via m-pair half2 writes (rows c = 0..7)
    for (int mp = tid; mp < 168; mp += 512) {
        int m0 = 2 * mp, m1 = 2 * mp + 1;
        half4_t v0a = z4, v0b = z4, v1a = z4, v1b = z4;
        if (m0 < NN) {
            v0a = *(const half4_t*)(v16g + qbase + m0 * 8);
            v0b = *(const half4_t*)(v16g + qbase + m0 * 8 + 4);
        }
        if (m1 < NN) {
            v1a = *(const half4_t*)(v16g + qbase + m1 * 8);
            v1b = *(const half4_t*)(v16g + qbase + m1 * 8 + 4);
        }
        #pragma unroll
        for (int c = 0; c < 4; ++c) {
            half2_t p0; p0[0] = v0a[c]; p0[1] = v1a[c];
            half2_t p1; p1[0] = v0b[c]; p1[1] = v1b[c];
            *(half2_t*)&VT16[c * 344 + 2 * mp]       = p0;
            *(half2_t*)&VT16[(c + 4) * 344 + 2 * mp] = p1;
        }
    }

    // block max of |k|^2 (wave butterfly + 8-word LDS, reusing the barrier)
    #pragma unroll
    for (int off = 32; off >= 1; off >>= 1)
        nk2 = fmaxf(nk2, __shfl_xor(nk2, off, 64));
    if ((tid & 63) == 0) smax8[tid >> 6] = nk2;
    __syncthreads();

    const float maxk2 = fmaxf(
        fmaxf(fmaxf(smax8[0], smax8[1]), fmaxf(smax8[2], smax8[3])),
        fmaxf(fmaxf(smax8[4], smax8[5]), fmaxf(smax8[6], smax8[7])));

    const int lane = tid & 63;
    const int wv   = tid >> 6;     // 0..7
    const int l15  = lane & 15;
    const int quad = lane >> 4;
    const int qsh  = quad * 4;

    for (int t = wv; t < 21; t += 8) {
        const int n  = t * 16 + l15;
        const int nq = (n < NN) ? n : (NN - 1);   // clamp for global reads

        half4_t qf = z4;
        if (quad < 2)
            qf = *(const half4_t*)(q16g + qbase + (long)nq * 8 + qsh);

        // rm = |q_n| * max_m|k_m|  (upper bound on all scores for row n)
        float ssq = 0.0f;
        #pragma unroll
        for (int j = 0; j < 4; ++j) {
            float fq = (float)qf[j];
            ssq = fmaf(fq, fq, ssq);
        }
        ssq += __shfl_xor(ssq, 16, 64);
        ssq += __shfl_xor(ssq, 32, 64);
        const float rm = sqrtf(ssq * maxk2);

        // mask words: latency hides under the score MFMAs
        unsigned int mb[11];
        #pragma unroll
        for (int w = 0; w < 11; ++w) mb[w] = packedT[w * NN + nq];

        // single pass: s' = K.Q^T - rm (C-operand), p = exp2(s'), ones-row sum
        const float4_t cinit = {-rm, -rm, -rm, -rm};
        float4_t acc = {0.f, 0.f, 0.f, 0.f};
        #pragma unroll
        for (int mt = 0; mt < 21; ++mt) {
            half4_t kf = *(const half4_t*)&K16[(mt * 16 + l15) * 20 + qsh];
            float4_t sv = __builtin_amdgcn_mfma_f32_16x16x16f16(
                kf, qf, cinit, 0, 0, 0);
            unsigned int sh = mb[mt >> 1] >> (((mt & 1) << 4) + qsh);
            float p0 = (sh & 1u) ? __builtin_amdgcn_exp2f(sv[0]) : 0.f;
            float p1 = (sh & 2u) ? __builtin_amdgcn_exp2f(sv[1]) : 0.f;
            float p2 = (sh & 4u) ? __builtin_amdgcn_exp2f(sv[2]) : 0.f;
            float p3 = (sh & 8u) ? __builtin_amdgcn_exp2f(sv[3]) : 0.f;
            half4_t pf;
            pf[0] = (half_t)p0; pf[1] = (half_t)p1;
            pf[2] = (half_t)p2; pf[3] = (half_t)p3;
            half4_t vf = *(const half4_t*)&VT16[l15 * 344 + mt * 16 + qsh];
            acc = __builtin_amdgcn_mfma_f32_16x16x16f16(vf, pf, acc, 0, 0, 0);
        }

        // sum for row n lives in lane (quad=2).acc[0]  (ones row c=8)
        float sum = __shfl(acc[0], 32 + l15, 64);

        if (quad < 2 && n < NN) {
            float inv = 1.0f / sum;
            half4_t o;
            o[0] = (half_t)(acc[0] * inv); o[1] = (half_t)(acc[1] * inv);
            o[2] = (half_t)(acc[2] * inv); o[3] = (half_t)(acc[3] * inv);
            *(half4_t*)(ao + baseO + (long)n * 64 + qsh) = o;
        }
    }
}

// ---------------------------------------------------------------------------
// Kernel 3: out = gelu(ao @ W10.T + b10) @ W11.T + b11 (r9 structure).
// ---------------------------------------------------------------------------
__global__ __launch_bounds__(512) void proj_kernel(
    const half_t* __restrict__ ao, const half_t* __restrict__ wab,
    const float* __restrict__ b10, const float* __restrict__ b11,
    float* __restrict__ out)
{
    __shared__ __attribute__((aligned(16))) half_t a16[64 * PS];
    __shared__ __attribute__((aligned(16))) half_t wA[64 * PS];
    __shared__ __attribute__((aligned(16))) half_t wB[64 * PS];
    __shared__ __attribute__((aligned(16))) half_t h16[64 * PS];
    const int tid  = threadIdx.x;
    const int row0 = blockIdx.x * 64;

    for (int idx = tid; idx < 512; idx += 512) {
        int r = idx >> 3, c8 = idx & 7;
        int R = row0 + r;
        uint4 u = {0u, 0u, 0u, 0u};
        if (R < NROWS) u = *(const uint4*)(ao + (long)R * 64 + c8 * 8);
        *(uint4*)&a16[r * PS + c8 * 8] = u;
        *(uint4*)&wA[r * PS + c8 * 8] = *(const uint4*)&wab[r * 64 + c8 * 8];
        *(uint4*)&wB[r * PS + c8 * 8] = *(const uint4*)&wab[4096 + r * 64 + c8 * 8];
    }
    __syncthreads();

    const int lane = tid & 63, wv = tid >> 6;
    const int l15 = lane & 15, quad = lane >> 4;
    const int rbase = (wv & 3) * 16, ch = wv >> 2;

    // stage 1: h = gelu(a @ W10.T + b10)
    float4_t acc[2];
    #pragma unroll
    for (int cc = 0; cc < 2; ++cc) {
        float bias = b10[(ch * 2 + cc) * 16 + l15];
        acc[cc] = (float4_t){bias, bias, bias, bias};
    }
    #pragma unroll
    for (int kk = 0; kk < 4; ++kk) {
        half4_t a = *(const half4_t*)&a16[(rbase + l15) * PS + kk * 16 + quad * 4];
        #pragma unroll
        for (int cc = 0; cc < 2; ++cc) {
            half4_t bf = *(const half4_t*)
                &wA[((ch * 2 + cc) * 16 + l15) * PS + kk * 16 + quad * 4];
            acc[cc] = __builtin_amdgcn_mfma_f32_16x16x16f16(a, bf, acc[cc], 0, 0, 0);
        }
    }
    #pragma unroll
    for (int cc = 0; cc < 2; ++cc) {
        #pragma unroll
        for (int rr = 0; rr < 4; ++rr)
            h16[(rbase + quad * 4 + rr) * PS + (ch * 2 + cc) * 16 + l15] =
                (half_t)gelu_f(acc[cc][rr]);
    }
    __syncthreads();

    // stage 2: out = h @ W11.T + b11
    #pragma unroll
    for (int cc = 0; cc < 2; ++cc) {
        float bias = b11[(ch * 2 + cc) * 16 + l15];
        acc[cc] = (float4_t){bias, bias, bias, bias};
    }
    #pragma unroll
    for (int kk = 0; kk < 4; ++kk) {
        half4_t a = *(const half4_t*)&h16[(rbase + l15) * PS + kk * 16 + quad * 4];
        #pragma unroll
        for (int cc = 0; cc < 2; ++cc) {
            half4_t bf = *(const half4_t*)
                &wB[((ch * 2 + cc) * 16 + l15) * PS + kk * 16 + quad * 4];
            acc[cc] = __builtin_amdgcn_mfma_f32_16x16x16f16(a, bf, acc[cc], 0, 0, 0);
        }
    }
    #pragma unroll
    for (int cc = 0; cc < 2; ++cc) {
        #pragma unroll
        for (int rr = 0; rr < 4; ++rr) {
            int R = row0 + rbase + quad * 4 + rr;
            if (R < NROWS)
                out[R * 64 + (ch * 2 + cc) * 16 + l15] = acc[cc][rr];
        }
    }
}

extern "C" void kernel_launch(void* const* d_in, const int* in_sizes, int n_in,
                              void* d_out, int out_size, void* d_ws, size_t ws_size,
                              hipStream_t stream) {
    const float* X   = (const float*)d_in[0];
    const float* STE = (const float*)d_in[1];
    const int*   adj = (const int*)d_in[2];
    const float* W7  = (const float*)d_in[3];
    const float* b7  = (const float*)d_in[4];
    const float* W8  = (const float*)d_in[5];
    const float* b8  = (const float*)d_in[6];
    const float* W9  = (const float*)d_in[7];
    const float* b9  = (const float*)d_in[8];
    const float* W10 = (const float*)d_in[9];
    const float* b10 = (const float*)d_in[10];
    const float* W11 = (const float*)d_in[11];
    const float* b11 = (const float*)d_in[12];

    char* wsb = (char*)d_ws;
    const long S = (long)NROWS * 64;           // 1,996,800 elements
    half_t* qb = (half_t*)wsb;
    half_t* kb = qb + S;
    half_t* vb = qb + 2 * S;
    half_t* ab = qb + 3 * S;
    unsigned int* pk = (unsigned int*)(wsb + 4 * S * sizeof(half_t));
    half_t* wab = (half_t*)(wsb + 4 * S * sizeof(half_t) + 16384);

    qkv_kernel<<<dim3(TOT_BLKS), 512, 0, stream>>>(
        X, STE, adj, W7, b7, W8, b8, W9, b9, W10, W11,
        qb, kb, vb, pk, wab);
    attn_kernel<<<dim3(8 * BT), 512, 0, stream>>>(qb, kb, vb, pk, ab);
    proj_kernel<<<dim3((NROWS + 63) / 64), 512, 0, stream>>>(
        ab, wab, b10, b11, (float*)d_out);
}